// Round 12
// baseline (186.934 us; speedup 1.0000x reference)
//
#include <hip/hip_runtime.h>
#include <hip/hip_bf16.h>

typedef short short4v __attribute__((ext_vector_type(4)));
typedef short short8v __attribute__((ext_vector_type(8)));
typedef float floatx4 __attribute__((ext_vector_type(4)));
typedef unsigned int uint2v __attribute__((ext_vector_type(2)));

#define SLEN 1024
#define DDIM 64
#define NBH  128

__device__ __forceinline__ unsigned short f2bf(float f) {
  union { float f; unsigned int u; } v; v.f = f;
  unsigned int u = v.u;
  u += 0x7fffu + ((u >> 16) & 1u);   // RNE
  return (unsigned short)(u >> 16);
}

// packed fp32x2 -> bf16x2 (RNE); low short = first arg
__device__ __forceinline__ unsigned int pkbf(float a, float b) {
  __hip_bfloat162 h = __float22bfloat162_rn(float2{a, b});
  union { __hip_bfloat162 h; unsigned int u; } c; c.h = h;
  return c.u;
}

// cross-lane riffles (gfx950): a,b both updated. Harness-verified (R3/R8).
__device__ __forceinline__ void pl32sw(unsigned int &a, unsigned int &b) {
#if __has_builtin(__builtin_amdgcn_permlane32_swap)
  uint2v r = __builtin_amdgcn_permlane32_swap(a, b, false, false);
  a = r[0]; b = r[1];
#else
  asm volatile("s_nop 1\n\tv_permlane32_swap_b32 %0, %1" : "+v"(a), "+v"(b));
#endif
}
__device__ __forceinline__ void pl16sw(unsigned int &a, unsigned int &b) {
#if __has_builtin(__builtin_amdgcn_permlane16_swap)
  uint2v r = __builtin_amdgcn_permlane16_swap(a, b, false, false);
  a = r[0]; b = r[1];
#else
  asm volatile("s_nop 1\n\tv_permlane16_swap_b32 %0, %1" : "+v"(a), "+v"(b));
#endif
}

__device__ __forceinline__ int decode_vl(const int* __restrict__ vraw, int bh) {
  const bool is64 = (vraw[1] == 0) && (vraw[3] == 0) && (vraw[5] == 0) && (vraw[7] == 0);
  const int b = bh >> 4;
  return is64 ? vraw[2 * b] : vraw[b];
}
__device__ __forceinline__ int nch_of(const int* __restrict__ vraw, int bh) {
  const int v = decode_vl(vraw, bh);
  return (v >> 6) + ((v & 63) ? 1 : 0);
}

// ---- prep: SV2[bh][d] = sum over masked-tail chunks [nch,16) of V column d ----
__global__ __launch_bounds__(256)
void prep(const float* __restrict__ Vg, const int* __restrict__ vraw,
          float* __restrict__ SV2) {
  const int bh = blockIdx.x;
  const int d  = threadIdx.x & 63;
  const int cg = threadIdx.x >> 6;            // 4 chunk-lanes
  const int ts = nch_of(vraw, bh);
  float sum = 0.f;
  for (int ch = ts + cg; ch < 16; ch += 4) {
    const float* src = Vg + (size_t)(bh * SLEN + ch * 64) * DDIM + d;
    #pragma unroll
    for (int k = 0; k < 64; ++k) sum += src[(size_t)k * DDIM];
  }
  __shared__ float red[4][64];
  red[cg][d] = sum;
  __syncthreads();
  if (cg == 0)
    SV2[(size_t)bh * 64 + d] = (red[0][d] + red[1][d]) + (red[2][d] + red[3][d]);
}

// ---------------- main: fused flash attention, no-max softmax ----------------
// R8 core + DOUBLE-BUFFERED STAGING REGISTERS: loads for chunk c issued at iter
// c-3 (~2.7 iterations of vmcnt slack vs ~1 before) to ride out load-queue
// latency under full-chip load. setprio removed (harmful in lockstep barriers,
// m190). Natural task order (R11: sorted order quadruples L2 misses).
__global__ __launch_bounds__(256)
void attn_main(const float* __restrict__ Qg, const float* __restrict__ Kg,
               const float* __restrict__ Vg, const float* __restrict__ SV,
               const int* __restrict__ vraw, float* __restrict__ Og)
{
  __shared__ unsigned short K_lds[2][4096];     // 64x64 bf16 swizzled, double-buffered
  __shared__ unsigned short VT_lds[2][4096];    // total 32 KB

  const int t  = threadIdx.x;
  const int ww = t >> 6;
  const int ln = t & 15;
  const int g  = (t >> 4) & 3;

  const int bh = blockIdx.x & 127;              // natural order: q-siblings in lockstep
  const int q0 = (blockIdx.x >> 7) * 128;

  const int vl          = decode_vl(vraw, bh);
  const int full_ch     = vl >> 6;
  const int has_partial = (vl & 63) ? 1 : 0;
  const int nch         = SV ? (full_ch + has_partial) : 16;
  const int tail_start  = full_ch + has_partial;

  // Q as B-operand fragments, pre-scaled by (1/8)*log2(e) so softmax = exp2.
  const float qs = 0.125f * 1.44269504f;
  short8v bq[2][2];
  #pragma unroll
  for (int nt = 0; nt < 2; ++nt) {
    const float* qp = Qg + ((size_t)bh * SLEN + q0 + ww * 32 + nt * 16 + ln) * DDIM;
    #pragma unroll
    for (int st = 0; st < 2; ++st) {
      const float4 f0 = *(const float4*)(qp + st * 32 + g * 8);
      const float4 f1 = *(const float4*)(qp + st * 32 + g * 8 + 4);
      short8v a;
      a[0]=(short)f2bf(f0.x*qs); a[1]=(short)f2bf(f0.y*qs);
      a[2]=(short)f2bf(f0.z*qs); a[3]=(short)f2bf(f0.w*qs);
      a[4]=(short)f2bf(f1.x*qs); a[5]=(short)f2bf(f1.y*qs);
      a[6]=(short)f2bf(f1.z*qs); a[7]=(short)f2bf(f1.w*qs);
      bq[nt][st] = a;
    }
  }

  const int l7  = ln & 7;
  const int sw0 = ((g) ^ l7) * 8;       // granule g   (keys/d 0..31 half)
  const int sw1 = ((4 + g) ^ l7) * 8;   // granule 4+g (keys/d 32..63 half)

  short8v ones;   // bf16 1.0 x8 : A-operand for row-sum MFMA (all rows equal)
  #pragma unroll
  for (int j = 0; j < 8; ++j) ones[j] = (short)0x3F80;

  // O^T fragments: ot[nt][f] holds O^T[d = f*16 + g*4 + i][q = nt*16 + ln]
  floatx4 ot[2][4], lacc[2];
  #pragma unroll
  for (int m = 0; m < 2; ++m) {
    lacc[m] = (floatx4){0.f, 0.f, 0.f, 0.f};
    #pragma unroll
    for (int f = 0; f < 4; ++f) ot[m][f] = (floatx4){0.f, 0.f, 0.f, 0.f};
  }

  // ---- TWO staging register sets (compile-time indexed; rule #20) ----
  float kra[2][8], krb[2][8];
  float vloa[8], vhia[8], vlob[8], vhib[8];
  const int dv = t & 31;
  const int gv = t >> 5;
  const float* kbB = Kg + (size_t)bh * SLEN * DDIM;
  const float* vbB = Vg + (size_t)bh * SLEN * DDIM;

  auto stage_load = [&](int ch, float (&kr)[2][8], float (&vlo)[8], float (&vhi)[8]) {
    const float* kb_ = kbB + (size_t)ch * 64 * DDIM;
    const float* vb_ = vbB + (size_t)ch * 64 * DDIM;
    #pragma unroll
    for (int h = 0; h < 2; ++h) {
      const int q = t + h * 256;
      const int r = q >> 3, gr = q & 7;
      const float4 f0 = *(const float4*)(kb_ + r * DDIM + gr * 8);
      const float4 f1 = *(const float4*)(kb_ + r * DDIM + gr * 8 + 4);
      kr[h][0]=f0.x; kr[h][1]=f0.y; kr[h][2]=f0.z; kr[h][3]=f0.w;
      kr[h][4]=f1.x; kr[h][5]=f1.y; kr[h][6]=f1.z; kr[h][7]=f1.w;
    }
    #pragma unroll
    for (int j = 0; j < 8; ++j) {
      vlo[j] = vb_[(gv * 8 + j) * DDIM + dv];
      vhi[j] = vb_[(gv * 8 + j) * DDIM + dv + 32];
    }
  };
  auto stage_write = [&](int b, float (&kr)[2][8], float (&vlo)[8], float (&vhi)[8]) {
    #pragma unroll
    for (int h = 0; h < 2; ++h) {
      const int q = t + h * 256;
      const int r = q >> 3, gr = q & 7;
      union { short8v s; unsigned int u[4]; } ks;
      ks.u[0] = pkbf(kr[h][0], kr[h][1]);
      ks.u[1] = pkbf(kr[h][2], kr[h][3]);
      ks.u[2] = pkbf(kr[h][4], kr[h][5]);
      ks.u[3] = pkbf(kr[h][6], kr[h][7]);
      *(short8v*)&K_lds[b][r * 64 + ((gr ^ (r & 7)) * 8)] = ks.s;
    }
    union { short8v s; unsigned int u[4]; } va, vb2;
    va.u[0]  = pkbf(vlo[0], vlo[1]); va.u[1]  = pkbf(vlo[2], vlo[3]);
    va.u[2]  = pkbf(vlo[4], vlo[5]); va.u[3]  = pkbf(vlo[6], vlo[7]);
    vb2.u[0] = pkbf(vhi[0], vhi[1]); vb2.u[1] = pkbf(vhi[2], vhi[3]);
    vb2.u[2] = pkbf(vhi[4], vhi[5]); vb2.u[3] = pkbf(vhi[6], vhi[7]);
    const int swv = (gv ^ (dv & 7)) * 8;
    *(short8v*)&VT_lds[b][dv * 64 + swv] = va.s;
    *(short8v*)&VT_lds[b][(dv + 32) * 64 + swv] = vb2.s;
  };

  // one iteration of the chunk loop; all buffer/set indices compile-time constant
  auto iter = [&](int ch, int b,
                  float (&wkr)[2][8], float (&wvlo)[8], float (&wvhi)[8],   // write set
                  float (&lkr)[2][8], float (&lvlo)[8], float (&lvhi)[8]) { // same set, reloaded
    // write chunk ch+1 from regs loaded at iter ch-2 (~2.7 iters of slack);
    // then reload the same set with chunk ch+3 (consumed at iter ch+2).
    if (ch + 1 < nch) stage_write(b ^ 1, wkr, wvlo, wvhi);
    if (ch + 3 < nch) stage_load(ch + 3, lkr, lvlo, lvhi);

    // ---- S^T = K * Q^T ----
    floatx4 c[4][2];
    #pragma unroll
    for (int mt = 0; mt < 4; ++mt) {
      const short8v a0 = *(const short8v*)&K_lds[b][(mt * 16 + ln) * 64 + sw0];
      const short8v a1 = *(const short8v*)&K_lds[b][(mt * 16 + ln) * 64 + sw1];
      #pragma unroll
      for (int nt = 0; nt < 2; ++nt) {
        floatx4 acc = (floatx4){0.f, 0.f, 0.f, 0.f};
        acc = __builtin_amdgcn_mfma_f32_16x16x32_bf16(a0, bq[nt][0], acc, 0, 0, 0);
        acc = __builtin_amdgcn_mfma_f32_16x16x32_bf16(a1, bq[nt][1], acc, 0, 0, 0);
        c[mt][nt] = acc;
      }
    }

    // ---- p = exp2(s) (masked -> exp2(0) = 1.0), packed cvt to bf16 pairs ----
    unsigned int pk0[4][2], pk1[4][2];
    const bool fullv = (ch < full_ch);
    #pragma unroll
    for (int mt = 0; mt < 4; ++mt) {
      const int kg = ch * 64 + mt * 16 + g * 4;
      #pragma unroll
      for (int nt = 0; nt < 2; ++nt) {
        float p[4];
        if (fullv) {
          #pragma unroll
          for (int i = 0; i < 4; ++i) p[i] = __builtin_amdgcn_exp2f(c[mt][nt][i]);
        } else {
          #pragma unroll
          for (int i = 0; i < 4; ++i) {
            const float x = (kg + i < vl) ? c[mt][nt][i] : 0.0f;
            p[i] = __builtin_amdgcn_exp2f(x);
          }
        }
        pk0[mt][nt] = pkbf(p[0], p[1]);
        pk1[mt][nt] = pkbf(p[2], p[3]);
      }
    }

    // ---- in-register P^T B-fragment build (permlane riffles, no LDS) ----
    short8v bp[2][2];
    #pragma unroll
    for (int st = 0; st < 2; ++st) {
      #pragma unroll
      for (int nt = 0; nt < 2; ++nt) {
        unsigned int a0 = pk0[2 * st][nt], b0 = pk0[2 * st + 1][nt];
        unsigned int a1 = pk1[2 * st][nt], b1 = pk1[2 * st + 1][nt];
        pl32sw(a0, b0); pl16sw(a0, b0);   // a0 -> keys {0,1}, b0 -> keys {4,5}
        pl32sw(a1, b1); pl16sw(a1, b1);   // a1 -> keys {2,3}, b1 -> keys {6,7}
        union { short8v s; unsigned int u[4]; } bb;
        bb.u[0] = a0; bb.u[1] = a1; bb.u[2] = b0; bb.u[3] = b1;
        bp[st][nt] = bb.s;
      }
    }

    // ---- O^T += V^T * P^T ; l += ones * P^T (all rows of lacc equal l_q) ----
    #pragma unroll
    for (int st = 0; st < 2; ++st) {
      lacc[0] = __builtin_amdgcn_mfma_f32_16x16x32_bf16(ones, bp[st][0], lacc[0], 0, 0, 0);
      lacc[1] = __builtin_amdgcn_mfma_f32_16x16x32_bf16(ones, bp[st][1], lacc[1], 0, 0, 0);
      const int sw = (st == 0) ? sw0 : sw1;
      #pragma unroll
      for (int f = 0; f < 4; ++f) {
        const short8v av = *(const short8v*)&VT_lds[b][(f * 16 + ln) * 64 + sw];
        ot[0][f] = __builtin_amdgcn_mfma_f32_16x16x32_bf16(av, bp[st][0], ot[0][f], 0, 0, 0);
        ot[1][f] = __builtin_amdgcn_mfma_f32_16x16x32_bf16(av, bp[st][1], ot[1][f], 0, 0, 0);
      }
    }

    if (ch + 1 < nch) {
      asm volatile("s_waitcnt lgkmcnt(0)" ::: "memory");
      __builtin_amdgcn_s_barrier();
      asm volatile("" ::: "memory");
    }
  };

  // prologue: chunk0 -> setA (written immediately); chunk1 -> setB; chunk2 -> setA
  if (nch > 0) {
    stage_load(0, kra, vloa, vhia);
    stage_write(0, kra, vloa, vhia);
    if (nch > 1) stage_load(1, krb, vlob, vhib);
    if (nch > 2) stage_load(2, kra, vloa, vhia);
    asm volatile("s_waitcnt lgkmcnt(0)" ::: "memory");
    __builtin_amdgcn_s_barrier();
    asm volatile("" ::: "memory");
  }

  // main loop, unrolled by 2 so staging-set indices are compile-time constants.
  // ch even: buffer 0, write/reload set B (chunk ch+1 odd); ch odd: buffer 1, set A.
  {
    int ch = 0;
    while (ch < nch) {
      iter(ch, 0, krb, vlob, vhib, krb, vlob, vhib);
      ++ch;
      if (ch >= nch) break;
      iter(ch, 1, kra, vloa, vhia, kra, vloa, vhia);
      ++ch;
    }
  }

  // ---- fully-masked tail: O^T += suffix colsum of V, l += #masked ----
  if (SV != nullptr && tail_start < 16) {
    const float* sv = SV + (size_t)bh * 64 + g * 4;
    float4 sv4[4];
    #pragma unroll
    for (int f = 0; f < 4; ++f) sv4[f] = *(const float4*)(sv + f * 16);
    const float ml = (float)(SLEN - tail_start * 64);
    #pragma unroll
    for (int nt = 0; nt < 2; ++nt) {
      #pragma unroll
      for (int i = 0; i < 4; ++i) lacc[nt][i] += ml;
      #pragma unroll
      for (int f = 0; f < 4; ++f) {
        ot[nt][f][0] += sv4[f].x; ot[nt][f][1] += sv4[f].y;
        ot[nt][f][2] += sv4[f].z; ot[nt][f][3] += sv4[f].w;
      }
    }
  }

  // ---- epilogue: O = O^T / l ; lane writes float4 (4 consecutive d) ----
  #pragma unroll
  for (int nt = 0; nt < 2; ++nt) {
    const float inv = 1.0f / lacc[nt][0];
    float* orow = Og + ((size_t)bh * SLEN + q0 + ww * 32 + nt * 16 + ln) * DDIM + g * 4;
    #pragma unroll
    for (int f = 0; f < 4; ++f) {
      float4 v4;
      v4.x = ot[nt][f][0] * inv; v4.y = ot[nt][f][1] * inv;
      v4.z = ot[nt][f][2] * inv; v4.w = ot[nt][f][3] * inv;
      *(float4*)(orow + f * 16) = v4;
    }
  }
}

extern "C" void kernel_launch(void* const* d_in, const int* in_sizes, int n_in,
                              void* d_out, int out_size, void* d_ws, size_t ws_size,
                              hipStream_t stream) {
  const float* Q = (const float*)d_in[0];
  const float* K = (const float*)d_in[1];
  const float* V = (const float*)d_in[2];
  const int*  vl = (const int*)d_in[3];
  float* out = (float*)d_out;

  const size_t ws_all = (size_t)NBH * 64 * 4;   // SV2: 32,768 B

  if (ws_size >= ws_all) {
    float* SV2 = (float*)d_ws;
    prep<<<NBH, 256, 0, stream>>>(V, vl, SV2);
    attn_main<<<dim3(1024), dim3(256), 0, stream>>>(Q, K, V, SV2, vl, out);
  } else {
    attn_main<<<dim3(1024), dim3(256), 0, stream>>>(Q, K, V, nullptr, vl, out);
  }
}

// Round 13
// 152.082 us; speedup vs baseline: 1.2292x; 1.2292x over previous
//
#include <hip/hip_runtime.h>
#include <hip/hip_bf16.h>

typedef short short4v __attribute__((ext_vector_type(4)));
typedef short short8v __attribute__((ext_vector_type(8)));
typedef float floatx4 __attribute__((ext_vector_type(4)));
typedef unsigned int uint2v __attribute__((ext_vector_type(2)));

#define SLEN 1024
#define DDIM 64
#define NBH  128

__device__ __forceinline__ unsigned short f2bf(float f) {
  union { float f; unsigned int u; } v; v.f = f;
  unsigned int u = v.u;
  u += 0x7fffu + ((u >> 16) & 1u);   // RNE
  return (unsigned short)(u >> 16);
}

// packed fp32x2 -> bf16x2 (RNE); low short = first arg
__device__ __forceinline__ unsigned int pkbf(float a, float b) {
  __hip_bfloat162 h = __float22bfloat162_rn(float2{a, b});
  union { __hip_bfloat162 h; unsigned int u; } c; c.h = h;
  return c.u;
}

// cross-lane riffles (gfx950): a,b both updated. Harness-verified (R3/R8).
__device__ __forceinline__ void pl32sw(unsigned int &a, unsigned int &b) {
#if __has_builtin(__builtin_amdgcn_permlane32_swap)
  uint2v r = __builtin_amdgcn_permlane32_swap(a, b, false, false);
  a = r[0]; b = r[1];
#else
  asm volatile("s_nop 1\n\tv_permlane32_swap_b32 %0, %1" : "+v"(a), "+v"(b));
#endif
}
__device__ __forceinline__ void pl16sw(unsigned int &a, unsigned int &b) {
#if __has_builtin(__builtin_amdgcn_permlane16_swap)
  uint2v r = __builtin_amdgcn_permlane16_swap(a, b, false, false);
  a = r[0]; b = r[1];
#else
  asm volatile("s_nop 1\n\tv_permlane16_swap_b32 %0, %1" : "+v"(a), "+v"(b));
#endif
}

__device__ __forceinline__ int decode_vl(const int* __restrict__ vraw, int bh) {
  const bool is64 = (vraw[1] == 0) && (vraw[3] == 0) && (vraw[5] == 0) && (vraw[7] == 0);
  const int b = bh >> 4;
  return is64 ? vraw[2 * b] : vraw[b];
}
__device__ __forceinline__ int nch_of(const int* __restrict__ vraw, int bh) {
  const int v = decode_vl(vraw, bh);
  return (v >> 6) + ((v & 63) ? 1 : 0);
}

// ---- prepass 1: per-(bh,ch) colsums of V fp32 for tail chunks only (R8 verbatim) ----
__global__ __launch_bounds__(64)
void prep_cs(const float* __restrict__ Vg, float* __restrict__ CS,
             const int* __restrict__ vraw) {
  const int tile = blockIdx.x;                 // (bh,ch)
  const int bh = tile >> 4, ch = tile & 15;
  const int d = threadIdx.x;
  const int ts = nch_of(vraw, bh);
  float sum = 0.f;
  if (ch >= ts) {
    const float* src = Vg + (size_t)(bh * SLEN + ch * 64) * DDIM + d;
    float s0 = 0.f, s1 = 0.f, s2 = 0.f, s3 = 0.f;
    #pragma unroll
    for (int k = 0; k < 64; k += 4) {
      s0 += src[(size_t)(k + 0) * DDIM];
      s1 += src[(size_t)(k + 1) * DDIM];
      s2 += src[(size_t)(k + 2) * DDIM];
      s3 += src[(size_t)(k + 3) * DDIM];
    }
    sum = (s0 + s1) + (s2 + s3);
  }
  CS[(size_t)tile * 64 + d] = sum;
}

// ---- prepass 2: suffix sums + per-XCD LPT sort table (R8 verbatim) ----
__global__ __launch_bounds__(64)
void prep_sv(float* __restrict__ CS, const int* __restrict__ vraw, int* __restrict__ SRT) {
  const int blk = blockIdx.x;
  if (blk < NBH) {
    const int d = threadIdx.x;
    float acc = 0.f;
    for (int ch = 15; ch >= 0; --ch) {
      const size_t idx = ((size_t)blk * 16 + ch) * 64 + d;
      acc += CS[idx];
      CS[idx] = acc;
    }
  } else {
    const int x = threadIdx.x;
    if (x < 8) {
      int key[16];
      #pragma unroll
      for (int k = 0; k < 16; ++k) key[k] = nch_of(vraw, x + 8 * k);
      #pragma unroll
      for (int i = 0; i < 16; ++i) {
        int rank = 0;
        #pragma unroll
        for (int k2 = 0; k2 < 16; ++k2)
          rank += (int)((key[k2] > key[i]) || (key[k2] == key[i] && k2 < i));
        SRT[x * 16 + rank] = x + 8 * i;
      }
    }
  }
}

// ---------------- main: fused flash attention, no-max softmax ----------------
// R8 per-wave core verbatim; block widened to 512 threads (8 waves) covering
// 256 q-rows. K/V staging amortized over 2x compute: each thread stages ONE
// K-granule + ONE V-column (half of R8) -> staging VMEM/VALU and L2 demand
// halve while per-wave registers DROP. Grid 512 = 2 blocks/CU, LDS 32KB.
__global__ __launch_bounds__(512)
void attn_main(const float* __restrict__ Qg, const float* __restrict__ Kg,
               const float* __restrict__ Vg, const float* __restrict__ SV,
               const int* __restrict__ SRT, const int* __restrict__ vraw,
               float* __restrict__ Og)
{
  __shared__ unsigned short K_lds[2][4096];     // 64x64 bf16 swizzled, double-buffered
  __shared__ unsigned short VT_lds[2][4096];    // total 32 KB

  const int t  = threadIdx.x;                   // 0..511
  const int ww = t >> 6;                        // wave 0..7 -> q-rows ww*32..+31
  const int ln = t & 15;
  const int g  = (t >> 4) & 3;

  // task decode: XCD-local + LPT snake (R8's scheme, 4 q-halves of 256 rows)
  int bh, q0;
  if (SRT) {
    const int xcd  = blockIdx.x & 7;
    const int lidx = blockIdx.x >> 3;           // 0..63
    const int cu   = lidx & 31;
    const int j    = lidx >> 5;                 // 0..1
    const int r    = j * 32 + ((j & 1) ? (31 - cu) : cu);   // 0..63
    bh = SRT[xcd * 16 + (r >> 2)];
    q0 = (r & 3) * 256;
  } else {
    bh = blockIdx.x & 127;
    q0 = (blockIdx.x >> 7) * 256;
  }

  const int vl          = decode_vl(vraw, bh);
  const int full_ch     = vl >> 6;
  const int has_partial = (vl & 63) ? 1 : 0;
  const int nch         = SV ? (full_ch + has_partial) : 16;
  const int tail_start  = full_ch + has_partial;

  // Q as B-operand fragments, pre-scaled by (1/8)*log2(e) so softmax = exp2.
  const float qs = 0.125f * 1.44269504f;
  short8v bq[2][2];
  #pragma unroll
  for (int nt = 0; nt < 2; ++nt) {
    const float* qp = Qg + ((size_t)bh * SLEN + q0 + ww * 32 + nt * 16 + ln) * DDIM;
    #pragma unroll
    for (int st = 0; st < 2; ++st) {
      const float4 f0 = *(const float4*)(qp + st * 32 + g * 8);
      const float4 f1 = *(const float4*)(qp + st * 32 + g * 8 + 4);
      short8v a;
      a[0]=(short)f2bf(f0.x*qs); a[1]=(short)f2bf(f0.y*qs);
      a[2]=(short)f2bf(f0.z*qs); a[3]=(short)f2bf(f0.w*qs);
      a[4]=(short)f2bf(f1.x*qs); a[5]=(short)f2bf(f1.y*qs);
      a[6]=(short)f2bf(f1.z*qs); a[7]=(short)f2bf(f1.w*qs);
      bq[nt][st] = a;
    }
  }

  const int l7  = ln & 7;
  const int sw0 = ((g) ^ l7) * 8;       // granule g   (keys/d 0..31 half)
  const int sw1 = ((4 + g) ^ l7) * 8;   // granule 4+g (keys/d 32..63 half)

  short8v ones;   // bf16 1.0 x8 : A-operand for row-sum MFMA (all rows equal)
  #pragma unroll
  for (int j = 0; j < 8; ++j) ones[j] = (short)0x3F80;

  // O^T fragments: ot[nt][f] holds O^T[d = f*16 + g*4 + i][q = nt*16 + ln]
  floatx4 ot[2][4], lacc[2];
  #pragma unroll
  for (int m = 0; m < 2; ++m) {
    lacc[m] = (floatx4){0.f, 0.f, 0.f, 0.f};
    #pragma unroll
    for (int f = 0; f < 4; ++f) ot[m][f] = (floatx4){0.f, 0.f, 0.f, 0.f};
  }

  // ---- staging registers (HALF of R8): 1 K granule (q = t) + 1 V column ----
  float kr[8];
  float vcol[8];
  const int kra_r = t >> 3, kra_g = t & 7;      // K row, granule (512 granules total)
  const int dv = t & 63;                        // V column 0..63
  const int gv = t >> 6;                        // V key-granule 0..7
  const float* kbB = Kg + (size_t)bh * SLEN * DDIM;
  const float* vbB = Vg + (size_t)bh * SLEN * DDIM;

  auto stage_load = [&](int ch) {
    const float* kb_ = kbB + (size_t)ch * 64 * DDIM;
    const float* vb_ = vbB + (size_t)ch * 64 * DDIM;
    const float4 f0 = *(const float4*)(kb_ + kra_r * DDIM + kra_g * 8);
    const float4 f1 = *(const float4*)(kb_ + kra_r * DDIM + kra_g * 8 + 4);
    kr[0]=f0.x; kr[1]=f0.y; kr[2]=f0.z; kr[3]=f0.w;
    kr[4]=f1.x; kr[5]=f1.y; kr[6]=f1.z; kr[7]=f1.w;
    #pragma unroll
    for (int j = 0; j < 8; ++j)                 // coalesced: 64 lanes = 64 consecutive d
      vcol[j] = vb_[(gv * 8 + j) * DDIM + dv];
  };
  auto stage_write = [&](int b) {
    union { short8v s; unsigned int u[4]; } ks;
    ks.u[0] = pkbf(kr[0], kr[1]); ks.u[1] = pkbf(kr[2], kr[3]);
    ks.u[2] = pkbf(kr[4], kr[5]); ks.u[3] = pkbf(kr[6], kr[7]);
    *(short8v*)&K_lds[b][kra_r * 64 + ((kra_g ^ (kra_r & 7)) * 8)] = ks.s;
    union { short8v s; unsigned int u[4]; } vs;
    vs.u[0] = pkbf(vcol[0], vcol[1]); vs.u[1] = pkbf(vcol[2], vcol[3]);
    vs.u[2] = pkbf(vcol[4], vcol[5]); vs.u[3] = pkbf(vcol[6], vcol[7]);
    *(short8v*)&VT_lds[b][dv * 64 + ((gv ^ (dv & 7)) * 8)] = vs.s;
  };

  // prologue: chunk 0 staged sync; chunk 1 loads in flight across the barrier
  if (nch > 0) {
    stage_load(0);
    stage_write(0);
    if (nch > 1) stage_load(1);
    asm volatile("s_waitcnt lgkmcnt(0)" ::: "memory");
    __builtin_amdgcn_s_barrier();
    asm volatile("" ::: "memory");
  }

  for (int ch = 0; ch < nch; ++ch) {
    const int b = ch & 1;
    if (ch + 1 < nch) stage_write(b ^ 1);     // regs loaded a full iteration ago
    if (ch + 2 < nch) stage_load(ch + 2);     // issue early; hides under compute

    // ---- S^T = K * Q^T ----
    floatx4 c[4][2];
    __builtin_amdgcn_s_setprio(1);
    #pragma unroll
    for (int mt = 0; mt < 4; ++mt) {
      const short8v a0 = *(const short8v*)&K_lds[b][(mt * 16 + ln) * 64 + sw0];
      const short8v a1 = *(const short8v*)&K_lds[b][(mt * 16 + ln) * 64 + sw1];
      #pragma unroll
      for (int nt = 0; nt < 2; ++nt) {
        floatx4 acc = (floatx4){0.f, 0.f, 0.f, 0.f};
        acc = __builtin_amdgcn_mfma_f32_16x16x32_bf16(a0, bq[nt][0], acc, 0, 0, 0);
        acc = __builtin_amdgcn_mfma_f32_16x16x32_bf16(a1, bq[nt][1], acc, 0, 0, 0);
        c[mt][nt] = acc;
      }
    }
    __builtin_amdgcn_s_setprio(0);

    // ---- p = exp2(s) (masked -> exp2(0) = 1.0), packed cvt to bf16 pairs ----
    unsigned int pk0[4][2], pk1[4][2];
    const bool fullv = (ch < full_ch);
    #pragma unroll
    for (int mt = 0; mt < 4; ++mt) {
      const int kg = ch * 64 + mt * 16 + g * 4;
      #pragma unroll
      for (int nt = 0; nt < 2; ++nt) {
        float p[4];
        if (fullv) {
          #pragma unroll
          for (int i = 0; i < 4; ++i) p[i] = __builtin_amdgcn_exp2f(c[mt][nt][i]);
        } else {
          #pragma unroll
          for (int i = 0; i < 4; ++i) {
            const float x = (kg + i < vl) ? c[mt][nt][i] : 0.0f;
            p[i] = __builtin_amdgcn_exp2f(x);
          }
        }
        pk0[mt][nt] = pkbf(p[0], p[1]);
        pk1[mt][nt] = pkbf(p[2], p[3]);
      }
    }

    // ---- in-register P^T B-fragment build (permlane riffles, no LDS) ----
    short8v bp[2][2];
    #pragma unroll
    for (int st = 0; st < 2; ++st) {
      #pragma unroll
      for (int nt = 0; nt < 2; ++nt) {
        unsigned int a0 = pk0[2 * st][nt], b0 = pk0[2 * st + 1][nt];
        unsigned int a1 = pk1[2 * st][nt], b1 = pk1[2 * st + 1][nt];
        pl32sw(a0, b0); pl16sw(a0, b0);   // a0 -> keys {0,1}, b0 -> keys {4,5}
        pl32sw(a1, b1); pl16sw(a1, b1);   // a1 -> keys {2,3}, b1 -> keys {6,7}
        union { short8v s; unsigned int u[4]; } bb;
        bb.u[0] = a0; bb.u[1] = a1; bb.u[2] = b0; bb.u[3] = b1;
        bp[st][nt] = bb.s;
      }
    }

    // ---- O^T += V^T * P^T ; l += ones * P^T (all rows of lacc equal l_q) ----
    __builtin_amdgcn_s_setprio(1);
    #pragma unroll
    for (int st = 0; st < 2; ++st) {
      lacc[0] = __builtin_amdgcn_mfma_f32_16x16x32_bf16(ones, bp[st][0], lacc[0], 0, 0, 0);
      lacc[1] = __builtin_amdgcn_mfma_f32_16x16x32_bf16(ones, bp[st][1], lacc[1], 0, 0, 0);
      const int sw = (st == 0) ? sw0 : sw1;
      #pragma unroll
      for (int f = 0; f < 4; ++f) {
        const short8v av = *(const short8v*)&VT_lds[b][(f * 16 + ln) * 64 + sw];
        ot[0][f] = __builtin_amdgcn_mfma_f32_16x16x32_bf16(av, bp[st][0], ot[0][f], 0, 0, 0);
        ot[1][f] = __builtin_amdgcn_mfma_f32_16x16x32_bf16(av, bp[st][1], ot[1][f], 0, 0, 0);
      }
    }
    __builtin_amdgcn_s_setprio(0);

    if (ch + 1 < nch) {
      asm volatile("s_waitcnt lgkmcnt(0)" ::: "memory");
      __builtin_amdgcn_s_barrier();
      asm volatile("" ::: "memory");
    }
  }

  // ---- fully-masked tail: O^T += suffix colsum of V, l += #masked ----
  if (SV != nullptr && tail_start < 16) {
    const float* sv = SV + ((size_t)bh * 16 + tail_start) * 64 + g * 4;
    float4 sv4[4];
    #pragma unroll
    for (int f = 0; f < 4; ++f) sv4[f] = *(const float4*)(sv + f * 16);
    const float ml = (float)(SLEN - tail_start * 64);
    #pragma unroll
    for (int nt = 0; nt < 2; ++nt) {
      #pragma unroll
      for (int i = 0; i < 4; ++i) lacc[nt][i] += ml;
      #pragma unroll
      for (int f = 0; f < 4; ++f) {
        ot[nt][f][0] += sv4[f].x; ot[nt][f][1] += sv4[f].y;
        ot[nt][f][2] += sv4[f].z; ot[nt][f][3] += sv4[f].w;
      }
    }
  }

  // ---- epilogue: O = O^T / l ; lane writes float4 (4 consecutive d) ----
  #pragma unroll
  for (int nt = 0; nt < 2; ++nt) {
    const float inv = 1.0f / lacc[nt][0];
    float* orow = Og + ((size_t)bh * SLEN + q0 + ww * 32 + nt * 16 + ln) * DDIM + g * 4;
    #pragma unroll
    for (int f = 0; f < 4; ++f) {
      float4 v4;
      v4.x = ot[nt][f][0] * inv; v4.y = ot[nt][f][1] * inv;
      v4.z = ot[nt][f][2] * inv; v4.w = ot[nt][f][3] * inv;
      *(float4*)(orow + f * 16) = v4;
    }
  }
}

extern "C" void kernel_launch(void* const* d_in, const int* in_sizes, int n_in,
                              void* d_out, int out_size, void* d_ws, size_t ws_size,
                              hipStream_t stream) {
  const float* Q = (const float*)d_in[0];
  const float* K = (const float*)d_in[1];
  const float* V = (const float*)d_in[2];
  const int*  vl = (const int*)d_in[3];
  float* out = (float*)d_out;

  const size_t ws_cs  = (size_t)NBH * 16 * 64 * 4;     // 524,288 B (chunk colsums)
  const size_t ws_all = ws_cs + 8 * 16 * 4;            // +512 B (LPT sort table)

  if (ws_size >= ws_all) {
    float* CS  = (float*)d_ws;
    int*   SRT = (int*)((char*)d_ws + ws_cs);
    prep_cs<<<2048, 64, 0, stream>>>(V, CS, vl);
    prep_sv<<<NBH + 1, 64, 0, stream>>>(CS, vl, SRT);
    attn_main<<<dim3(512), dim3(512), 0, stream>>>(Q, K, V, CS, SRT, vl, out);
  } else {
    attn_main<<<dim3(512), dim3(512), 0, stream>>>(Q, K, V, nullptr, nullptr, vl, out);
  }
}